// Round 1
// baseline (1125.099 us; speedup 1.0000x reference)
//
#include <hip/hip_runtime.h>
#include <hip/hip_bf16.h>
#include <math.h>

// Problem constants (B,T,D,H) = (64,128,512,2048), all fp32 in/out.
#define B_ 64
#define T_ 128
#define D_ 512
#define H_ 2048

typedef __bf16 bf16_t;
typedef __attribute__((ext_vector_type(8)))  __bf16 bf16x8;   // 4 VGPRs, MFMA A/B operand
typedef __attribute__((ext_vector_type(16))) float  f32x16;   // MFMA 32x32 accumulator

__device__ __forceinline__ float gelu_exact(float v) {
    // torch nn.GELU default: 0.5*x*(1+erf(x/sqrt(2)))
    return 0.5f * v * (1.0f + erff(v * 0.70710678118654752f));
}

// 8 consecutive fp32 -> bf16x8 (A-operand: contiguous K)
__device__ __forceinline__ bf16x8 load_cvt8_contig(const float* __restrict__ p) {
    const float4 lo = *(const float4*)p;
    const float4 hi = *(const float4*)(p + 4);
    bf16x8 r;
    r[0] = (bf16_t)lo.x; r[1] = (bf16_t)lo.y; r[2] = (bf16_t)lo.z; r[3] = (bf16_t)lo.w;
    r[4] = (bf16_t)hi.x; r[5] = (bf16_t)hi.y; r[6] = (bf16_t)hi.z; r[7] = (bf16_t)hi.w;
    return r;
}

// 8 fp32 strided by `stride` elements -> bf16x8 (B-operand: K-strided rows of W).
// Lanes 0..31 have consecutive addresses -> each of the 8 loads is a full
// 128B line per half-wave; weights are read exactly once chip-wide.
__device__ __forceinline__ bf16x8 load_cvt8_strided(const float* __restrict__ p, int stride) {
    float f[8];
    #pragma unroll
    for (int j = 0; j < 8; ++j) f[j] = p[(size_t)j * stride];
    bf16x8 r;
    #pragma unroll
    for (int j = 0; j < 8; ++j) r[j] = (bf16_t)f[j];
    return r;
}

// ---------------------------------------------------------------------------
// K1: h[t][b][n] = gelu( sum_k x[b][t][k] * W1[t][k][n] + b1[t][n] ), bf16 out
// grid = T*16 (each block: one token, 128 of 2048 H-cols, all 64 B-rows)
// block = 256 (4 waves; wave w owns n-cols [nb*128 + w*32, +32), both 32-row
// M-tiles). No LDS, no barriers — pure streaming.
// ---------------------------------------------------------------------------
__global__ __launch_bounds__(256) void ffn_k1(
    const float* __restrict__ x, const float* __restrict__ W1,
    const float* __restrict__ b1, bf16_t* __restrict__ h) {
    const int blk  = blockIdx.x;
    const int t    = blk >> 4;
    const int nb   = blk & 15;
    const int wave = threadIdx.x >> 6;
    const int lane = threadIdx.x & 63;
    const int nl   = lane & 31;   // MFMA n (B-operand) / output col
    const int ko   = lane >> 5;   // K-half selector: k = ko*8 + j
    const int n0   = nb * 128 + wave * 32;

    // A rows: x[b][t][k] at ((b*T + t)*D + k); m-tile0 rows 0..31, tile1 32..63
    const float* a0p = x + ((size_t)nl * T_ + t) * D_ + ko * 8;
    const float* a1p = x + ((size_t)(nl + 32) * T_ + t) * D_ + ko * 8;
    // B: W1[t][k][n], row stride H_
    const float* bp  = W1 + (size_t)t * D_ * H_ + (size_t)(ko * 8) * H_ + (n0 + nl);

    f32x16 acc0, acc1;
    #pragma unroll
    for (int i = 0; i < 16; ++i) { acc0[i] = 0.0f; acc1[i] = 0.0f; }

    for (int k0 = 0; k0 < D_; k0 += 16) {
        bf16x8 a0 = load_cvt8_contig(a0p);
        bf16x8 a1 = load_cvt8_contig(a1p);
        bf16x8 bb = load_cvt8_strided(bp, H_);
        acc0 = __builtin_amdgcn_mfma_f32_32x32x16_bf16(a0, bb, acc0, 0, 0, 0);
        acc1 = __builtin_amdgcn_mfma_f32_32x32x16_bf16(a1, bb, acc1, 0, 0, 0);
        a0p += 16; a1p += 16; bp += (size_t)16 * H_;
    }

    // Epilogue: bias + exact GELU, store h as bf16 [t][64][H] (K2's A layout)
    const float bias = b1[t * H_ + n0 + nl];
    bf16_t* hp = h + (size_t)t * (B_ * H_) + (n0 + nl);
    #pragma unroll
    for (int r = 0; r < 16; ++r) {
        // C/D layout (m74/m101): row=(r&3)+4*(lane>>5)+8*(r>>2), col=lane&31
        const int row = (r & 3) + 4 * ko + 8 * (r >> 2);
        hp[(size_t)row * H_]        = (bf16_t)gelu_exact(acc0[r] + bias);
        hp[(size_t)(row + 32) * H_] = (bf16_t)gelu_exact(acc1[r] + bias);
    }
}

// ---------------------------------------------------------------------------
// K2: out[b][t][d] = sum_k h[t][b][k] * W2[t][k][d] + b2[t][d], fp32 out
// grid = T*4 (each block: one token, 128 of 512 D-cols, all 64 B-rows)
// ---------------------------------------------------------------------------
__global__ __launch_bounds__(256) void ffn_k2(
    const bf16_t* __restrict__ h, const float* __restrict__ W2,
    const float* __restrict__ b2, float* __restrict__ out) {
    const int blk  = blockIdx.x;
    const int t    = blk >> 2;
    const int nb   = blk & 3;
    const int wave = threadIdx.x >> 6;
    const int lane = threadIdx.x & 63;
    const int nl   = lane & 31;
    const int ko   = lane >> 5;
    const int n0   = nb * 128 + wave * 32;

    // A: h[t][b][k] bf16, row stride H_; 16B-aligned contiguous frag loads
    const bf16_t* a0p = h + (size_t)t * (B_ * H_) + (size_t)nl * H_ + ko * 8;
    const bf16_t* a1p = a0p + (size_t)32 * H_;
    // B: W2[t][k][d], row stride D_
    const float* bp = W2 + (size_t)t * H_ * D_ + (size_t)(ko * 8) * D_ + (n0 + nl);

    f32x16 acc0, acc1;
    #pragma unroll
    for (int i = 0; i < 16; ++i) { acc0[i] = 0.0f; acc1[i] = 0.0f; }

    for (int k0 = 0; k0 < H_; k0 += 16) {
        bf16x8 a0 = *(const bf16x8*)a0p;
        bf16x8 a1 = *(const bf16x8*)a1p;
        bf16x8 bb = load_cvt8_strided(bp, D_);
        acc0 = __builtin_amdgcn_mfma_f32_32x32x16_bf16(a0, bb, acc0, 0, 0, 0);
        acc1 = __builtin_amdgcn_mfma_f32_32x32x16_bf16(a1, bb, acc1, 0, 0, 0);
        a0p += 16; a1p += 16; bp += (size_t)16 * D_;
    }

    const float bias = b2[t * D_ + n0 + nl];
    // out[b][t][d] at ((b*T + t)*D + d); row (b) stride T_*D_
    float* op = out + ((size_t)t * D_) + (n0 + nl);
    #pragma unroll
    for (int r = 0; r < 16; ++r) {
        const int row = (r & 3) + 4 * ko + 8 * (r >> 2);
        op[(size_t)row * (T_ * D_)]        = acc0[r] + bias;
        op[(size_t)(row + 32) * (T_ * D_)] = acc1[r] + bias;
    }
}

// ---------------------------------------------------------------------------
extern "C" void kernel_launch(void* const* d_in, const int* in_sizes, int n_in,
                              void* d_out, int out_size, void* d_ws, size_t ws_size,
                              hipStream_t stream) {
    const float* x  = (const float*)d_in[0];
    const float* W1 = (const float*)d_in[1];
    const float* b1 = (const float*)d_in[2];
    const float* W2 = (const float*)d_in[3];
    const float* b2 = (const float*)d_in[4];
    float* out   = (float*)d_out;
    bf16_t* hws  = (bf16_t*)d_ws;   // needs T*B*H*2 = 32 MiB of scratch

    ffn_k1<<<dim3(T_ * 16), dim3(256), 0, stream>>>(x, W1, b1, hws);
    ffn_k2<<<dim3(T_ * 4),  dim3(256), 0, stream>>>(hws, W2, b2, out);
}